// Round 12
// baseline (292.941 us; speedup 1.0000x reference)
//
#include <hip/hip_runtime.h>

// EquivariantProductBasisBlock (MACE symmetric contraction, corr=3) + o3.Linear
// N=10000 nodes, C=128 channels, L=9 (lmax=2), E=5 elements, fp32 throughout.
//
// R12 changes vs R11 (everything frozen except one knob):
//  - contract: NPT 4->2. XS LDS 36->18 KB (total ~26.5 KB): residency rises
//    from 3 blocks/CU (LDS-capped, 12 waves) to 4 (VGPR-capped, 16 waves),
//    grid doubles to ~2700 real blocks (smaller tail). LDS cb-issue per
//    u-iter (~180 cyc) stays below VALU (220 cyc) -> still VALU-bound, with
//    2x the waves to hide dependent-op latency.

#define CCH 128
#define LDIM 9
#define NE 5
#define BLK 256
#define NPT 2                // nodes per thread in contraction
#define UBLK 56              // packed floats per (dd,u)
#define DSTR 504             // per dd = 9*UBLK
#define GSTR 2016            // per (e,c) = 4*DSTR
#define U3LDS 8748           // staged U3 slice (729*12 max)

// tri(v,w) offset within u-block: entry (v,w>=v) at tri_off(v) + (w-v)
__host__ __device__ constexpr int tri_off(int v) {
  return 10 + v * 9 - v * (v - 1) / 2;
}

// -------------------------------------------- sort: count + offs (fused)
__global__ __launch_bounds__(BLK) void count_offs_kernel(
    const float* __restrict__ attrs, int N,
    int* __restrict__ elem, int* __restrict__ gcnt,   // gcnt[5], gcnt[5]=done
    int* __restrict__ offs, int* __restrict__ cur) {
  int n = blockIdx.x * BLK + threadIdx.x;
  int e = 0;
  if (n < N) {
    const float* a = attrs + n * NE;
#pragma unroll
    for (int j = 1; j < NE; ++j)
      if (a[j] > 0.5f) e = j;
    elem[n] = e;
  }
  int lane = threadIdx.x & 63;
#pragma unroll
  for (int k = 0; k < NE; ++k) {
    unsigned long long m = __ballot(n < N && e == k);
    if (m) {
      int leader = __ffsll((long long)m) - 1;
      if (lane == leader) atomicAdd(&gcnt[k], __popcll(m));
    }
  }
  __threadfence();
  __syncthreads();
  if (threadIdx.x == 0) {
    int t = atomicAdd(&gcnt[NE], 1);
    if (t == (int)gridDim.x - 1) {            // last block: prefix sum
      int acc = 0;
      for (int k = 0; k < NE; ++k) {
        int ck = atomicAdd(&gcnt[k], 0);      // coherent read
        offs[k] = acc; cur[k] = acc; acc += ck;
      }
      offs[NE] = acc;
    }
  }
}

// ----------------------------------------------------------- sort: scatter
__global__ __launch_bounds__(BLK) void scatter_kernel(
    const int* __restrict__ elem, int N,
    int* __restrict__ cur, int* __restrict__ order) {
  int n = blockIdx.x * BLK + threadIdx.x;
  if (n >= N) return;
  int e = elem[n];
  int lane = threadIdx.x & 63;
#pragma unroll
  for (int k = 0; k < NE; ++k) {
    if (e == k) {
      unsigned long long m = __ballot(1);
      int cnt = __popcll(m);
      int leader = __ffsll((long long)m) - 1;
      int base = 0;
      if (lane == leader) base = atomicAdd(&cur[k], cnt);
      base = __shfl(base, leader);
      int rank = __popcll(m & ((1ull << lane) - 1ull));
      order[base + rank] = n;
    }
  }
}

// ------------- build + (v,w)-symmetrize + pack U(x)w tables (one dd/block)
__global__ __launch_bounds__(BLK) void table_kernel(
    const float* __restrict__ U3_0, const float* __restrict__ U2_0,
    const float* __restrict__ U1_0, const float* __restrict__ U3_1,
    const float* __restrict__ U2_1, const float* __restrict__ U1_1,
    const float* __restrict__ w3_0, const float* __restrict__ w2_0,
    const float* __restrict__ w1_0, const float* __restrict__ w3_1,
    const float* __restrict__ w2_1, const float* __restrict__ w1_1,
    float* __restrict__ table) {
  const int b = blockIdx.x;        // e*CCH + c
  const int dd = blockIdx.y;       // 0..3
  const int e = b / CCH, c = b % CCH;
  float* Tg = table + (size_t)b * GSTR + dd * DSTR;
  __shared__ float Us[U3LDS];      // raw U3 slice [729*K3]
  __shared__ float U2s[324];       // raw U2 slice [81*K2]
  __shared__ float R3[729];        // rect T3
  __shared__ float R2[81];
  __shared__ float R1l[9];
  __shared__ float w3l[12], w2l[4];
  const int tid = threadIdx.x;
  const int d = dd - 1;
  const int K3 = (dd == 0) ? 10 : 12;
  const int K2 = (dd == 0) ? 3 : 4;

  if (dd == 0) {
    for (int i = tid; i < 7290; i += BLK) Us[i] = U3_0[i];
    for (int i = tid; i < 243; i += BLK)  U2s[i] = U2_0[i];
    if (tid < 10) w3l[tid] = w3_0[(e * 10 + tid) * CCH + c];
    else if (tid < 13) w2l[tid - 10] = w2_0[(e * 3 + (tid - 10)) * CCH + c];
    if (tid < 9) R1l[tid] = U1_0[tid] * w1_0[e * CCH + c];
  } else {
    for (int i = tid; i < 8748; i += BLK) Us[i] = U3_1[d * 8748 + i];
    for (int i = tid; i < 324; i += BLK)  U2s[i] = U2_1[d * 324 + i];
    if (tid < 12) w3l[tid] = w3_1[(e * 12 + tid) * CCH + c];
    else if (tid < 16) w2l[tid - 12] = w2_1[(e * 4 + (tid - 12)) * CCH + c];
    if (tid < 9) R1l[tid] = U1_1[d * 9 + tid] * w1_1[e * CCH + c];
  }
  __syncthreads();
  for (int r = tid; r < 729; r += BLK) {
    float acc = 0.f;
    for (int k = 0; k < K3; ++k) acc += Us[r * K3 + k] * w3l[k];
    R3[r] = acc;
  }
  for (int q = tid; q < 81; q += BLK) {
    float acc = 0.f;
    for (int k = 0; k < K2; ++k) acc += U2s[q * K2 + k] * w2l[k];
    R2[q] = acc;
  }
  __syncthreads();
  // pack per-u records: [T1 | T2[0..8] | tri S3 | pad]
  for (int i = tid; i < DSTR; i += BLK) {
    int u = i / UBLK, r = i % UBLK;
    float val = 0.f;
    if (r == 0) val = R1l[u];
    else if (r <= 9) val = R2[u * 9 + (r - 1)];
    else if (r <= 54) {
      int t = r - 10, v = 0;
      while (t >= 9 - v) { t -= 9 - v; ++v; }
      int w = v + t;
      val = (v == w) ? R3[(u * 9 + v) * 9 + v]
                     : R3[(u * 9 + v) * 9 + w] + R3[(u * 9 + w) * 9 + v];
    }
    Tg[i] = val;
  }
}

// --------------- symmetric contraction (tri-(v,w) Horner, rolled dd & u)
__global__ __launch_bounds__(BLK, 4) void contract_kernel(
    const float* __restrict__ feats, const float* __restrict__ table,
    const int* __restrict__ order, const int* __restrict__ offs,
    float* __restrict__ tmp, int NPAD) {
  const int c = blockIdx.x, e = blockIdx.z;     // c fastest -> dense dispatch
  const int start = offs[e], end = offs[e + 1];
  const int base = start + blockIdx.y * (BLK * NPT);
  if (base >= end) return;                      // block-uniform early exit

  __shared__ __align__(16) float T[GSTR];
  __shared__ float XS[BLK * NPT * LDIM];        // x staged for xu ds_read
  {
    const float4* src = (const float4*)(table + (size_t)(e * CCH + c) * GSTR);
    float4* dst = (float4*)T;
    for (int i = threadIdx.x; i < GSTR / 4; i += BLK) dst[i] = src[i];
  }

  const int tid = threadIdx.x;
  float x[NPT][LDIM];
  int pp[NPT];
  bool valid[NPT];
#pragma unroll
  for (int i = 0; i < NPT; ++i) {
    int p = base + i * BLK + tid;
    valid[i] = (p < end);
    int p2 = valid[i] ? p : (end - 1);          // clamp: stay in-bounds
    pp[i] = p;
    int n = order[p2];
    const float* xp = feats + ((size_t)n * CCH + c) * LDIM;
#pragma unroll
    for (int w = 0; w < LDIM; ++w) x[i][w] = xp[w];
#pragma unroll
    for (int w = 0; w < LDIM; ++w)
      XS[(i * BLK + tid) * LDIM + w] = x[i][w]; // stride-9: conflict-free
  }
  __syncthreads();

#pragma unroll 1
  for (int dd = 0; dd < 4; ++dd) {
    float accd[NPT];
#pragma unroll
    for (int i = 0; i < NPT; ++i) accd[i] = 0.f;
#pragma unroll 1
    for (int u = 0; u < 9; ++u) {
      const float* B = T + dd * DSTR + u * UBLK;   // 16B-aligned record
      float cb[UBLK];
#pragma unroll
      for (int q = 0; q < UBLK / 4; ++q) {
        float4 t = *(const float4*)(B + 4 * q);
        cb[4 * q + 0] = t.x; cb[4 * q + 1] = t.y;
        cb[4 * q + 2] = t.z; cb[4 * q + 3] = t.w;
      }
      // xu via LDS read (replaces 8-deep cndmask chain; stride-9 banks)
      float xu[NPT];
#pragma unroll
      for (int i = 0; i < NPT; ++i)
        xu[i] = XS[(i * BLK + tid) * LDIM + u];
      float inner[NPT];
#pragma unroll
      for (int i = 0; i < NPT; ++i) inner[i] = cb[0];   // T1[u]
#pragma unroll
      for (int v = 0; v < 9; ++v) {             // compile-time v
#pragma unroll
        for (int i = 0; i < NPT; ++i) {
          float Hv = cb[1 + v];                 // T2[u][v]
#pragma unroll
          for (int w = v; w < 9; ++w)           // compile-time w
            Hv = fmaf(cb[tri_off(v) + (w - v)], x[i][w], Hv);
          inner[i] = fmaf(Hv, x[i][v], inner[i]);
        }
      }
#pragma unroll
      for (int i = 0; i < NPT; ++i) accd[i] = fmaf(inner[i], xu[i], accd[i]);
    }
    float* o = tmp + (size_t)(dd * CCH + c) * NPAD;
#pragma unroll
    for (int i = 0; i < NPT; ++i)
      if (valid[i]) o[pp[i]] = accd[i];         // consecutive p -> coalesced
  }
}

// ------------- o3.Linear + residual: LDS-tiled GEMM, coalesced in and out
#define NB 16                 // nodes per block
__global__ __launch_bounds__(BLK, 4) void linear_kernel(
    const float* __restrict__ tmp, const float* __restrict__ W0,
    const float* __restrict__ W1, const float* __restrict__ sc,
    const int* __restrict__ order, float* __restrict__ out, int N, int NPAD) {
  const int p0 = blockIdx.x * NB;
  const int t = threadIdx.x;
  __shared__ __align__(16) float SU[8448];

  // ---- phase 1: stage A[dd][ci][j] = tmp[dd][ci][p0+j], coalesced float4
#pragma unroll
  for (int k = 0; k < 8; ++k) {
    int f = t + k * BLK;               // float4 index 0..2047
    int dd = f >> 9, r = f & 511;
    int ci = r >> 2, q = f & 3;
    float4 v = *(const float4*)(tmp + (size_t)(dd * CCH + ci) * NPAD + p0 + q * 4);
    *(float4*)(SU + dd * 2048 + ci * 16 + q * 4) = v;
  }
  __syncthreads();

  // ---- phase 2: thread = (node j, co-octet o). 32 FMA per ci.
  const int j = t & 15;                // node within tile
  const int o = t >> 4;                // 16 octets of 8 co
  float acc[4][8];
#pragma unroll
  for (int dd = 0; dd < 4; ++dd)
#pragma unroll
    for (int k = 0; k < 8; ++k) acc[dd][k] = 0.f;

  const float* W0p = W0 + o * 8;
  const float* W1p = W1 + o * 8;
#pragma unroll 2
  for (int ci = 0; ci < CCH; ++ci) {
    float a0 = SU[0 * 2048 + ci * 16 + j];
    float a1 = SU[1 * 2048 + ci * 16 + j];
    float a2 = SU[2 * 2048 + ci * 16 + j];
    float a3 = SU[3 * 2048 + ci * 16 + j];
    float4 wa = *(const float4*)(W0p + ci * CCH);
    float4 wb = *(const float4*)(W0p + ci * CCH + 4);
    float4 wc = *(const float4*)(W1p + ci * CCH);
    float4 wd = *(const float4*)(W1p + ci * CCH + 4);
    acc[0][0] = fmaf(a0, wa.x, acc[0][0]);
    acc[0][1] = fmaf(a0, wa.y, acc[0][1]);
    acc[0][2] = fmaf(a0, wa.z, acc[0][2]);
    acc[0][3] = fmaf(a0, wa.w, acc[0][3]);
    acc[0][4] = fmaf(a0, wb.x, acc[0][4]);
    acc[0][5] = fmaf(a0, wb.y, acc[0][5]);
    acc[0][6] = fmaf(a0, wb.z, acc[0][6]);
    acc[0][7] = fmaf(a0, wb.w, acc[0][7]);
    acc[1][0] = fmaf(a1, wc.x, acc[1][0]);
    acc[1][1] = fmaf(a1, wc.y, acc[1][1]);
    acc[1][2] = fmaf(a1, wc.z, acc[1][2]);
    acc[1][3] = fmaf(a1, wc.w, acc[1][3]);
    acc[1][4] = fmaf(a1, wd.x, acc[1][4]);
    acc[1][5] = fmaf(a1, wd.y, acc[1][5]);
    acc[1][6] = fmaf(a1, wd.z, acc[1][6]);
    acc[1][7] = fmaf(a1, wd.w, acc[1][7]);
    acc[2][0] = fmaf(a2, wc.x, acc[2][0]);
    acc[2][1] = fmaf(a2, wc.y, acc[2][1]);
    acc[2][2] = fmaf(a2, wc.z, acc[2][2]);
    acc[2][3] = fmaf(a2, wc.w, acc[2][3]);
    acc[2][4] = fmaf(a2, wd.x, acc[2][4]);
    acc[2][5] = fmaf(a2, wd.y, acc[2][5]);
    acc[2][6] = fmaf(a2, wd.z, acc[2][6]);
    acc[2][7] = fmaf(a2, wd.w, acc[2][7]);
    acc[3][0] = fmaf(a3, wc.x, acc[3][0]);
    acc[3][1] = fmaf(a3, wc.y, acc[3][1]);
    acc[3][2] = fmaf(a3, wc.z, acc[3][2]);
    acc[3][3] = fmaf(a3, wc.w, acc[3][3]);
    acc[3][4] = fmaf(a3, wd.x, acc[3][4]);
    acc[3][5] = fmaf(a3, wd.y, acc[3][5]);
    acc[3][6] = fmaf(a3, wd.z, acc[3][6]);
    acc[3][7] = fmaf(a3, wd.w, acc[3][7]);
  }
  __syncthreads();                     // A dead; SU becomes S[16][516]

  // ---- phase 3: assemble output rows in LDS
  const float s = 0.08838834764831843f;        // 1/sqrt(128)
  float* Sj = SU + j * 516;
#pragma unroll
  for (int k = 0; k < 8; ++k) {
    int co = o * 8 + k;
    Sj[co]               = acc[0][k] * s;
    Sj[CCH + co * 3 + 0] = acc[1][k] * s;
    Sj[CCH + co * 3 + 1] = acc[2][k] * s;
    Sj[CCH + co * 3 + 2] = acc[3][k] * s;
  }
  __syncthreads();

  // ---- phase 4: sc + write, full 512-float rows, float4-coalesced
  const int f = t & 127;               // float4 index within row
  const int jj = t >> 7;
#pragma unroll 1
  for (int jr = jj; jr < NB; jr += 2) {
    int p = p0 + jr;
    if (p < N) {
      int n = order[p];
      float4 sv = ((const float4*)(sc + (size_t)n * 512))[f];
      float4 ov = ((const float4*)(SU + jr * 516))[f];
      ov.x += sv.x; ov.y += sv.y; ov.z += sv.z; ov.w += sv.w;
      ((float4*)(out + (size_t)n * 512))[f] = ov;
    }
  }
}

// -------------------------------------------------------------------- launch
extern "C" void kernel_launch(void* const* d_in, const int* in_sizes, int n_in,
                              void* d_out, int out_size, void* d_ws, size_t ws_size,
                              hipStream_t stream) {
  const float* feats = (const float*)d_in[0];
  const float* attrs = (const float*)d_in[1];
  const float* sc    = (const float*)d_in[2];
  const float* U3_0  = (const float*)d_in[3];
  const float* U2_0  = (const float*)d_in[4];
  const float* U1_0  = (const float*)d_in[5];
  const float* w3_0  = (const float*)d_in[6];
  const float* w2_0  = (const float*)d_in[7];
  const float* w1_0  = (const float*)d_in[8];
  const float* U3_1  = (const float*)d_in[9];
  const float* U2_1  = (const float*)d_in[10];
  const float* U1_1  = (const float*)d_in[11];
  const float* w3_1  = (const float*)d_in[12];
  const float* w2_1  = (const float*)d_in[13];
  const float* w1_1  = (const float*)d_in[14];
  const float* W0    = (const float*)d_in[15];
  const float* W1    = (const float*)d_in[16];

  const int N = in_sizes[0] / (CCH * LDIM);     // 10000
  const int NPAD = ((N + 15) & ~15) + 16;

  // ws (floats): table[5*128*GSTR] | tmp[4*C][NPAD] | order elem offs(8) cur(8) gcnt(8)
  float* table = (float*)d_ws;
  float* tmp   = table + (size_t)NE * CCH * GSTR;
  int*   order = (int*)(tmp + (size_t)4 * CCH * NPAD);
  int*   elem  = order + N;
  int*   offs  = elem + N;
  int*   cur   = offs + 8;
  int*   gcnt  = cur + 8;                       // gcnt[0..4], gcnt[5]=done
  float* out   = (float*)d_out;

  hipMemsetAsync(gcnt, 0, 8 * sizeof(int), stream);

  const int nblk = (N + BLK - 1) / BLK;
  count_offs_kernel<<<dim3(nblk), dim3(BLK), 0, stream>>>(
      attrs, N, elem, gcnt, offs, cur);
  scatter_kernel<<<dim3(nblk), dim3(BLK), 0, stream>>>(elem, N, cur, order);

  table_kernel<<<dim3(NE * CCH, 4), dim3(BLK), 0, stream>>>(
      U3_0, U2_0, U1_0, U3_1, U2_1, U1_1,
      w3_0, w2_0, w1_0, w3_1, w2_1, w1_1, table);

  const int chunks = (N + BLK * NPT - 1) / (BLK * NPT);
  contract_kernel<<<dim3(CCH, chunks, NE), dim3(BLK), 0, stream>>>(
      feats, table, order, offs, tmp, NPAD);

  linear_kernel<<<dim3((N + NB - 1) / NB), dim3(BLK), 0, stream>>>(
      tmp, W0, W1, sc, order, out, N, NPAD);
}

// Round 13
// 287.043 us; speedup vs baseline: 1.0205x; 1.0205x over previous
//
#include <hip/hip_runtime.h>

// EquivariantProductBasisBlock (MACE symmetric contraction, corr=3) + o3.Linear
// N=10000 nodes, C=128 channels, L=9 (lmax=2), E=5 elements, fp32 throughout.
//
// R13 changes vs R12 (everything frozen except contract):
//  - R12 showed the LDS pipe is the contract limiter (occupancy 23->45% gave
//    NO speedup; cb reads per node doubled and saturated DS issue). Now cb
//    records are read DIRECTLY from global: the address is wave-uniform and
//    table is const __restrict__ -> backend's uniform-load opt emits
//    s_load_dwordx4 (SMEM path, SGPR results, zero LDS/VMEM-pipe cost;
//    v_fma takes one SGPR operand). T staging + its barrier removed (XS is
//    same-thread write/read -> no __syncthreads at all). NPT back to 4;
//    LDS = XS only (36 KB) -> 4 blocks/CU, 50% occupancy cap.

#define CCH 128
#define LDIM 9
#define NE 5
#define BLK 256
#define NPT 4                // nodes per thread in contraction
#define UBLK 56              // packed floats per (dd,u)
#define DSTR 504             // per dd = 9*UBLK
#define GSTR 2016            // per (e,c) = 4*DSTR
#define U3LDS 8748           // staged U3 slice (729*12 max)

// tri(v,w) offset within u-block: entry (v,w>=v) at tri_off(v) + (w-v)
__host__ __device__ constexpr int tri_off(int v) {
  return 10 + v * 9 - v * (v - 1) / 2;
}

// -------------------------------------------- sort: count + offs (fused)
__global__ __launch_bounds__(BLK) void count_offs_kernel(
    const float* __restrict__ attrs, int N,
    int* __restrict__ elem, int* __restrict__ gcnt,   // gcnt[5], gcnt[5]=done
    int* __restrict__ offs, int* __restrict__ cur) {
  int n = blockIdx.x * BLK + threadIdx.x;
  int e = 0;
  if (n < N) {
    const float* a = attrs + n * NE;
#pragma unroll
    for (int j = 1; j < NE; ++j)
      if (a[j] > 0.5f) e = j;
    elem[n] = e;
  }
  int lane = threadIdx.x & 63;
#pragma unroll
  for (int k = 0; k < NE; ++k) {
    unsigned long long m = __ballot(n < N && e == k);
    if (m) {
      int leader = __ffsll((long long)m) - 1;
      if (lane == leader) atomicAdd(&gcnt[k], __popcll(m));
    }
  }
  __threadfence();
  __syncthreads();
  if (threadIdx.x == 0) {
    int t = atomicAdd(&gcnt[NE], 1);
    if (t == (int)gridDim.x - 1) {            // last block: prefix sum
      int acc = 0;
      for (int k = 0; k < NE; ++k) {
        int ck = atomicAdd(&gcnt[k], 0);      // coherent read
        offs[k] = acc; cur[k] = acc; acc += ck;
      }
      offs[NE] = acc;
    }
  }
}

// ----------------------------------------------------------- sort: scatter
__global__ __launch_bounds__(BLK) void scatter_kernel(
    const int* __restrict__ elem, int N,
    int* __restrict__ cur, int* __restrict__ order) {
  int n = blockIdx.x * BLK + threadIdx.x;
  if (n >= N) return;
  int e = elem[n];
  int lane = threadIdx.x & 63;
#pragma unroll
  for (int k = 0; k < NE; ++k) {
    if (e == k) {
      unsigned long long m = __ballot(1);
      int cnt = __popcll(m);
      int leader = __ffsll((long long)m) - 1;
      int base = 0;
      if (lane == leader) base = atomicAdd(&cur[k], cnt);
      base = __shfl(base, leader);
      int rank = __popcll(m & ((1ull << lane) - 1ull));
      order[base + rank] = n;
    }
  }
}

// ------------- build + (v,w)-symmetrize + pack U(x)w tables (one dd/block)
__global__ __launch_bounds__(BLK) void table_kernel(
    const float* __restrict__ U3_0, const float* __restrict__ U2_0,
    const float* __restrict__ U1_0, const float* __restrict__ U3_1,
    const float* __restrict__ U2_1, const float* __restrict__ U1_1,
    const float* __restrict__ w3_0, const float* __restrict__ w2_0,
    const float* __restrict__ w1_0, const float* __restrict__ w3_1,
    const float* __restrict__ w2_1, const float* __restrict__ w1_1,
    float* __restrict__ table) {
  const int b = blockIdx.x;        // e*CCH + c
  const int dd = blockIdx.y;       // 0..3
  const int e = b / CCH, c = b % CCH;
  float* Tg = table + (size_t)b * GSTR + dd * DSTR;
  __shared__ float Us[U3LDS];      // raw U3 slice [729*K3]
  __shared__ float U2s[324];       // raw U2 slice [81*K2]
  __shared__ float R3[729];        // rect T3
  __shared__ float R2[81];
  __shared__ float R1l[9];
  __shared__ float w3l[12], w2l[4];
  const int tid = threadIdx.x;
  const int d = dd - 1;
  const int K3 = (dd == 0) ? 10 : 12;
  const int K2 = (dd == 0) ? 3 : 4;

  if (dd == 0) {
    for (int i = tid; i < 7290; i += BLK) Us[i] = U3_0[i];
    for (int i = tid; i < 243; i += BLK)  U2s[i] = U2_0[i];
    if (tid < 10) w3l[tid] = w3_0[(e * 10 + tid) * CCH + c];
    else if (tid < 13) w2l[tid - 10] = w2_0[(e * 3 + (tid - 10)) * CCH + c];
    if (tid < 9) R1l[tid] = U1_0[tid] * w1_0[e * CCH + c];
  } else {
    for (int i = tid; i < 8748; i += BLK) Us[i] = U3_1[d * 8748 + i];
    for (int i = tid; i < 324; i += BLK)  U2s[i] = U2_1[d * 324 + i];
    if (tid < 12) w3l[tid] = w3_1[(e * 12 + tid) * CCH + c];
    else if (tid < 16) w2l[tid - 12] = w2_1[(e * 4 + (tid - 12)) * CCH + c];
    if (tid < 9) R1l[tid] = U1_1[d * 9 + tid] * w1_1[e * CCH + c];
  }
  __syncthreads();
  for (int r = tid; r < 729; r += BLK) {
    float acc = 0.f;
    for (int k = 0; k < K3; ++k) acc += Us[r * K3 + k] * w3l[k];
    R3[r] = acc;
  }
  for (int q = tid; q < 81; q += BLK) {
    float acc = 0.f;
    for (int k = 0; k < K2; ++k) acc += U2s[q * K2 + k] * w2l[k];
    R2[q] = acc;
  }
  __syncthreads();
  // pack per-u records: [T1 | T2[0..8] | tri S3 | pad]
  for (int i = tid; i < DSTR; i += BLK) {
    int u = i / UBLK, r = i % UBLK;
    float val = 0.f;
    if (r == 0) val = R1l[u];
    else if (r <= 9) val = R2[u * 9 + (r - 1)];
    else if (r <= 54) {
      int t = r - 10, v = 0;
      while (t >= 9 - v) { t -= 9 - v; ++v; }
      int w = v + t;
      val = (v == w) ? R3[(u * 9 + v) * 9 + v]
                     : R3[(u * 9 + v) * 9 + w] + R3[(u * 9 + w) * 9 + v];
    }
    Tg[i] = val;
  }
}

// --- symmetric contraction (tri Horner; cb via uniform global load -> SMEM)
__global__ __launch_bounds__(BLK, 4) void contract_kernel(
    const float* __restrict__ feats, const float* __restrict__ table,
    const int* __restrict__ order, const int* __restrict__ offs,
    float* __restrict__ tmp, int NPAD) {
  const int c = blockIdx.x, e = blockIdx.z;     // c fastest -> dense dispatch
  const int start = offs[e], end = offs[e + 1];
  const int base = start + blockIdx.y * (BLK * NPT);
  if (base >= end) return;                      // block-uniform early exit

  __shared__ float XS[BLK * NPT * LDIM];        // x staged for xu ds_read
  const float* Tg = table + (size_t)(e * CCH + c) * GSTR;  // wave-uniform

  const int tid = threadIdx.x;
  float x[NPT][LDIM];
  int pp[NPT];
  bool valid[NPT];
#pragma unroll
  for (int i = 0; i < NPT; ++i) {
    int p = base + i * BLK + tid;
    valid[i] = (p < end);
    int p2 = valid[i] ? p : (end - 1);          // clamp: stay in-bounds
    pp[i] = p;
    int n = order[p2];
    const float* xp = feats + ((size_t)n * CCH + c) * LDIM;
#pragma unroll
    for (int w = 0; w < LDIM; ++w) x[i][w] = xp[w];
#pragma unroll
    for (int w = 0; w < LDIM; ++w)
      XS[(i * BLK + tid) * LDIM + w] = x[i][w]; // same-thread readback: no barrier
  }

#pragma unroll 1
  for (int dd = 0; dd < 4; ++dd) {
    float accd[NPT];
#pragma unroll
    for (int i = 0; i < NPT; ++i) accd[i] = 0.f;
#pragma unroll 1
    for (int u = 0; u < 9; ++u) {
      // cb record: wave-uniform address into read-only table -> s_load (SMEM)
      const float* B = Tg + dd * DSTR + u * UBLK;
      float cb[UBLK];
#pragma unroll
      for (int q = 0; q < UBLK / 4; ++q) {
        float4 t = *(const float4*)(B + 4 * q);
        cb[4 * q + 0] = t.x; cb[4 * q + 1] = t.y;
        cb[4 * q + 2] = t.z; cb[4 * q + 3] = t.w;
      }
      // xu via LDS read (runtime u index; stride-9 banks, conflict-free)
      float xu[NPT];
#pragma unroll
      for (int i = 0; i < NPT; ++i)
        xu[i] = XS[(i * BLK + tid) * LDIM + u];
      float inner[NPT];
#pragma unroll
      for (int i = 0; i < NPT; ++i) inner[i] = cb[0];   // T1[u]
#pragma unroll
      for (int v = 0; v < 9; ++v) {             // compile-time v
#pragma unroll
        for (int i = 0; i < NPT; ++i) {
          float Hv = cb[1 + v];                 // T2[u][v]
#pragma unroll
          for (int w = v; w < 9; ++w)           // compile-time w
            Hv = fmaf(cb[tri_off(v) + (w - v)], x[i][w], Hv);
          inner[i] = fmaf(Hv, x[i][v], inner[i]);
        }
      }
#pragma unroll
      for (int i = 0; i < NPT; ++i) accd[i] = fmaf(inner[i], xu[i], accd[i]);
    }
    float* o = tmp + (size_t)(dd * CCH + c) * NPAD;
#pragma unroll
    for (int i = 0; i < NPT; ++i)
      if (valid[i]) o[pp[i]] = accd[i];         // consecutive p -> coalesced
  }
}

// ------------- o3.Linear + residual: LDS-tiled GEMM, coalesced in and out
#define NB 16                 // nodes per block
__global__ __launch_bounds__(BLK, 4) void linear_kernel(
    const float* __restrict__ tmp, const float* __restrict__ W0,
    const float* __restrict__ W1, const float* __restrict__ sc,
    const int* __restrict__ order, float* __restrict__ out, int N, int NPAD) {
  const int p0 = blockIdx.x * NB;
  const int t = threadIdx.x;
  __shared__ __align__(16) float SU[8448];

  // ---- phase 1: stage A[dd][ci][j] = tmp[dd][ci][p0+j], coalesced float4
#pragma unroll
  for (int k = 0; k < 8; ++k) {
    int f = t + k * BLK;               // float4 index 0..2047
    int dd = f >> 9, r = f & 511;
    int ci = r >> 2, q = f & 3;
    float4 v = *(const float4*)(tmp + (size_t)(dd * CCH + ci) * NPAD + p0 + q * 4);
    *(float4*)(SU + dd * 2048 + ci * 16 + q * 4) = v;
  }
  __syncthreads();

  // ---- phase 2: thread = (node j, co-octet o). 32 FMA per ci.
  const int j = t & 15;                // node within tile
  const int o = t >> 4;                // 16 octets of 8 co
  float acc[4][8];
#pragma unroll
  for (int dd = 0; dd < 4; ++dd)
#pragma unroll
    for (int k = 0; k < 8; ++k) acc[dd][k] = 0.f;

  const float* W0p = W0 + o * 8;
  const float* W1p = W1 + o * 8;
#pragma unroll 2
  for (int ci = 0; ci < CCH; ++ci) {
    float a0 = SU[0 * 2048 + ci * 16 + j];
    float a1 = SU[1 * 2048 + ci * 16 + j];
    float a2 = SU[2 * 2048 + ci * 16 + j];
    float a3 = SU[3 * 2048 + ci * 16 + j];
    float4 wa = *(const float4*)(W0p + ci * CCH);
    float4 wb = *(const float4*)(W0p + ci * CCH + 4);
    float4 wc = *(const float4*)(W1p + ci * CCH);
    float4 wd = *(const float4*)(W1p + ci * CCH + 4);
    acc[0][0] = fmaf(a0, wa.x, acc[0][0]);
    acc[0][1] = fmaf(a0, wa.y, acc[0][1]);
    acc[0][2] = fmaf(a0, wa.z, acc[0][2]);
    acc[0][3] = fmaf(a0, wa.w, acc[0][3]);
    acc[0][4] = fmaf(a0, wb.x, acc[0][4]);
    acc[0][5] = fmaf(a0, wb.y, acc[0][5]);
    acc[0][6] = fmaf(a0, wb.z, acc[0][6]);
    acc[0][7] = fmaf(a0, wb.w, acc[0][7]);
    acc[1][0] = fmaf(a1, wc.x, acc[1][0]);
    acc[1][1] = fmaf(a1, wc.y, acc[1][1]);
    acc[1][2] = fmaf(a1, wc.z, acc[1][2]);
    acc[1][3] = fmaf(a1, wc.w, acc[1][3]);
    acc[1][4] = fmaf(a1, wd.x, acc[1][4]);
    acc[1][5] = fmaf(a1, wd.y, acc[1][5]);
    acc[1][6] = fmaf(a1, wd.z, acc[1][6]);
    acc[1][7] = fmaf(a1, wd.w, acc[1][7]);
    acc[2][0] = fmaf(a2, wc.x, acc[2][0]);
    acc[2][1] = fmaf(a2, wc.y, acc[2][1]);
    acc[2][2] = fmaf(a2, wc.z, acc[2][2]);
    acc[2][3] = fmaf(a2, wc.w, acc[2][3]);
    acc[2][4] = fmaf(a2, wd.x, acc[2][4]);
    acc[2][5] = fmaf(a2, wd.y, acc[2][5]);
    acc[2][6] = fmaf(a2, wd.z, acc[2][6]);
    acc[2][7] = fmaf(a2, wd.w, acc[2][7]);
    acc[3][0] = fmaf(a3, wc.x, acc[3][0]);
    acc[3][1] = fmaf(a3, wc.y, acc[3][1]);
    acc[3][2] = fmaf(a3, wc.z, acc[3][2]);
    acc[3][3] = fmaf(a3, wc.w, acc[3][3]);
    acc[3][4] = fmaf(a3, wd.x, acc[3][4]);
    acc[3][5] = fmaf(a3, wd.y, acc[3][5]);
    acc[3][6] = fmaf(a3, wd.z, acc[3][6]);
    acc[3][7] = fmaf(a3, wd.w, acc[3][7]);
  }
  __syncthreads();                     // A dead; SU becomes S[16][516]

  // ---- phase 3: assemble output rows in LDS
  const float s = 0.08838834764831843f;        // 1/sqrt(128)
  float* Sj = SU + j * 516;
#pragma unroll
  for (int k = 0; k < 8; ++k) {
    int co = o * 8 + k;
    Sj[co]               = acc[0][k] * s;
    Sj[CCH + co * 3 + 0] = acc[1][k] * s;
    Sj[CCH + co * 3 + 1] = acc[2][k] * s;
    Sj[CCH + co * 3 + 2] = acc[3][k] * s;
  }
  __syncthreads();

  // ---- phase 4: sc + write, full 512-float rows, float4-coalesced
  const int f = t & 127;               // float4 index within row
  const int jj = t >> 7;
#pragma unroll 1
  for (int jr = jj; jr < NB; jr += 2) {
    int p = p0 + jr;
    if (p < N) {
      int n = order[p];
      float4 sv = ((const float4*)(sc + (size_t)n * 512))[f];
      float4 ov = ((const float4*)(SU + jr * 516))[f];
      ov.x += sv.x; ov.y += sv.y; ov.z += sv.z; ov.w += sv.w;
      ((float4*)(out + (size_t)n * 512))[f] = ov;
    }
  }
}

// -------------------------------------------------------------------- launch
extern "C" void kernel_launch(void* const* d_in, const int* in_sizes, int n_in,
                              void* d_out, int out_size, void* d_ws, size_t ws_size,
                              hipStream_t stream) {
  const float* feats = (const float*)d_in[0];
  const float* attrs = (const float*)d_in[1];
  const float* sc    = (const float*)d_in[2];
  const float* U3_0  = (const float*)d_in[3];
  const float* U2_0  = (const float*)d_in[4];
  const float* U1_0  = (const float*)d_in[5];
  const float* w3_0  = (const float*)d_in[6];
  const float* w2_0  = (const float*)d_in[7];
  const float* w1_0  = (const float*)d_in[8];
  const float* U3_1  = (const float*)d_in[9];
  const float* U2_1  = (const float*)d_in[10];
  const float* U1_1  = (const float*)d_in[11];
  const float* w3_1  = (const float*)d_in[12];
  const float* w2_1  = (const float*)d_in[13];
  const float* w1_1  = (const float*)d_in[14];
  const float* W0    = (const float*)d_in[15];
  const float* W1    = (const float*)d_in[16];

  const int N = in_sizes[0] / (CCH * LDIM);     // 10000
  const int NPAD = ((N + 15) & ~15) + 16;

  // ws (floats): table[5*128*GSTR] | tmp[4*C][NPAD] | order elem offs(8) cur(8) gcnt(8)
  float* table = (float*)d_ws;
  float* tmp   = table + (size_t)NE * CCH * GSTR;
  int*   order = (int*)(tmp + (size_t)4 * CCH * NPAD);
  int*   elem  = order + N;
  int*   offs  = elem + N;
  int*   cur   = offs + 8;
  int*   gcnt  = cur + 8;                       // gcnt[0..4], gcnt[5]=done
  float* out   = (float*)d_out;

  hipMemsetAsync(gcnt, 0, 8 * sizeof(int), stream);

  const int nblk = (N + BLK - 1) / BLK;
  count_offs_kernel<<<dim3(nblk), dim3(BLK), 0, stream>>>(
      attrs, N, elem, gcnt, offs, cur);
  scatter_kernel<<<dim3(nblk), dim3(BLK), 0, stream>>>(elem, N, cur, order);

  table_kernel<<<dim3(NE * CCH, 4), dim3(BLK), 0, stream>>>(
      U3_0, U2_0, U1_0, U3_1, U2_1, U1_1,
      w3_0, w2_0, w1_0, w3_1, w2_1, w1_1, table);

  const int chunks = (N + BLK * NPT - 1) / (BLK * NPT);
  contract_kernel<<<dim3(CCH, chunks, NE), dim3(BLK), 0, stream>>>(
      feats, table, order, offs, tmp, NPAD);

  linear_kernel<<<dim3((N + NB - 1) / NB), dim3(BLK), 0, stream>>>(
      tmp, W0, W1, sc, order, out, N, NPAD);
}